// Round 7
// baseline (183.310 us; speedup 1.0000x reference)
//
#include <hip/hip_runtime.h>
#include <math.h>

// GradientBoostingLoss: per-row top-4 hardest negatives + logsumexp, mean over rows.
// R7: 16 lanes/row, 4 rows/wave. ROLLING 9-deep load window (issue 8, then
// {issue next, consume oldest}) -> peak liveness ~9 quads, enabling
// __launch_bounds__(256,6) = 6 waves/SIMD while keeping guaranteed deep MLP.
// Label + label-logit gathered first (consumption order == issue order).
// All-DPP 4-stage butterfly (zero DS ops). Partials + tiny reducer.

#define WPB 4   // waves per block (256 threads)

typedef float vf4 __attribute__((ext_vector_type(4)));

__device__ __forceinline__ float4 ntload(const float* p) {
    vf4 v = __builtin_nontemporal_load((const vf4*)p);
    return make_float4(v.x, v.y, v.z, v.w);
}

__device__ __forceinline__ void ce(float &a, float &b) {
    float hi = fmaxf(a, b), lo = fminf(a, b); a = hi; b = lo;
}

// Sort float4 descending: 5 compare-exchanges.
__device__ __forceinline__ void sort4d(float4 &v) {
    ce(v.x, v.y); ce(v.z, v.w); ce(v.x, v.z); ce(v.y, v.w); ce(v.y, v.z);
}

// Merge two sorted-desc top-4 lists -> sorted-desc top-4 of union (12 ops).
__device__ __forceinline__ void merge4(float o0, float o1, float o2, float o3,
                                       float &t0, float &t1, float &t2, float &t3) {
    float c0 = fmaxf(t0, o3);
    float c1 = fmaxf(t1, o2);
    float c2 = fmaxf(t2, o1);
    float c3 = fmaxf(t3, o0);
    float d0 = fmaxf(c0, c2), d2 = fminf(c0, c2);
    float d1 = fmaxf(c1, c3), d3 = fminf(c1, c3);
    t0 = fmaxf(d0, d1); t1 = fminf(d0, d1);
    t2 = fmaxf(d2, d3); t3 = fminf(d2, d3);
}

__device__ __forceinline__ void mrgv(float4 &d, const float4 s) {
    merge4(s.x, s.y, s.z, s.w, d.x, d.y, d.z, d.w);
}

// Mask the label element to -inf if it lives in quad q (value already gathered).
__device__ __forceinline__ void maskq(float4 &v, int q, int qL, int sub) {
    if (q == qL) {
        if      (sub == 0) v.x = -INFINITY;
        else if (sub == 1) v.y = -INFINITY;
        else if (sub == 2) v.z = -INFINITY;
        else               v.w = -INFINITY;
    }
}

// DPP cross-lane (row-local, VALU-speed). 0xB1=xor1, 0x4E=xor2, 0x124=row_ror:4, 0x128=row_ror:8.
template<int CTRL>
__device__ __forceinline__ float dppf(float x) {
    int i = __float_as_int(x);
    return __int_as_float(__builtin_amdgcn_update_dpp(i, i, CTRL, 0xF, 0xF, false));
}

// NQ = quads per row; requires 239 < NQ <= 256.
template<int NQ>
__global__ __launch_bounds__(256, 6) void topk16(
    const float* __restrict__ logits, const int* __restrict__ labels,
    float* __restrict__ partial, int B)
{
    static_assert(NQ > 239 && NQ <= 256, "topk16 requires 239 < NQ <= 256");
    const int wid  = threadIdx.x >> 6;
    const int lane = threadIdx.x & 63;
    const int s    = lane & 15;          // sublane within 16-lane row group
    const int g    = lane >> 4;          // row group 0..3

    const int rowraw = (blockIdx.x * WPB + wid) * 4 + g;
    const bool valid = rowraw < B;
    const int row    = valid ? rowraw : B - 1;
    const float* rowp = logits + (size_t)row * (size_t)(NQ * 4);

    // Label chain first: consumed first, so later data consumes need only
    // fine-grained vmcnt (no full drain).
    const int L  = labels[row];
    const int qL = L >> 2, sub = L & 3;
    const float lab = rowp[L];           // group-uniform address (broadcast)

    const bool v15 = (s + 240) < NQ;
    const int  q15 = v15 ? (s + 240) : (NQ - 1);

    #define LDJ(j) ntload(rowp + 4 * (s + 16 * (j)))

    // ---- rolling window: 8 loads up-front...
    float4 b0 = LDJ(0), b1 = LDJ(1), b2 = LDJ(2), b3 = LDJ(3);
    float4 b4 = LDJ(4), b5 = LDJ(5), b6 = LDJ(6), b7 = LDJ(7);

    // ...then alternate {issue next, consume oldest}. Peak ~9 quads live.
    // Evens merge into chain t, odds into chain u (ILP).
    float4 b8  = LDJ(8);
    maskq(b0, s,      qL, sub); sort4d(b0); float4 t = b0;
    float4 b9  = LDJ(9);
    maskq(b1, s + 16, qL, sub); sort4d(b1); float4 u = b1;
    float4 b10 = LDJ(10);
    maskq(b2, s + 32, qL, sub); sort4d(b2); mrgv(t, b2);
    float4 b11 = LDJ(11);
    maskq(b3, s + 48, qL, sub); sort4d(b3); mrgv(u, b3);
    float4 b12 = LDJ(12);
    maskq(b4, s + 64, qL, sub); sort4d(b4); mrgv(t, b4);
    float4 b13 = LDJ(13);
    maskq(b5, s + 80, qL, sub); sort4d(b5); mrgv(u, b5);
    float4 b14 = LDJ(14);
    maskq(b6, s + 96, qL, sub); sort4d(b6); mrgv(t, b6);
    float4 b15 = ntload(rowp + 4 * q15);
    maskq(b7, s + 112, qL, sub); sort4d(b7); mrgv(u, b7);

    // Tail consumes (window drains).
    maskq(b8,  s + 128, qL, sub); sort4d(b8);  mrgv(t, b8);
    maskq(b9,  s + 144, qL, sub); sort4d(b9);  mrgv(u, b9);
    maskq(b10, s + 160, qL, sub); sort4d(b10); mrgv(t, b10);
    maskq(b11, s + 176, qL, sub); sort4d(b11); mrgv(u, b11);
    maskq(b12, s + 192, qL, sub); sort4d(b12); mrgv(t, b12);
    maskq(b13, s + 208, qL, sub); sort4d(b13); mrgv(u, b13);
    maskq(b14, s + 224, qL, sub); sort4d(b14); mrgv(t, b14);
    maskq(b15, q15,     qL, sub);
    if (!v15) b15 = make_float4(-INFINITY, -INFINITY, -INFINITY, -INFINITY);
    sort4d(b15); mrgv(u, b15);
    mrgv(t, u);
    #undef LDJ
    float t0 = t.x, t1 = t.y, t2 = t.z, t3 = t.w;

    // 4-stage all-DPP butterfly within each 16-lane row group.
    // xor1, xor2 (quad-local), then ror:4 / ror:8 merge disjoint sets:
    // every source element counted exactly once (top-k-safe).
    #define BSTAGE(CTRL) do {                                                  \
        float o0 = dppf<CTRL>(t0), o1 = dppf<CTRL>(t1);                        \
        float o2 = dppf<CTRL>(t2), o3 = dppf<CTRL>(t3);                        \
        merge4(o0, o1, o2, o3, t0, t1, t2, t3);                                \
    } while (0)
    BSTAGE(0xB1);   // quad_perm [1,0,3,2] : xor 1
    BSTAGE(0x4E);   // quad_perm [2,3,0,1] : xor 2
    BSTAGE(0x124);  // row_ror:4
    BSTAGE(0x128);  // row_ror:8
    #undef BSTAGE

    // loss = logsumexp([lab, t0..t3]) - lab (uniform across the 16-lane group)
    float mx = fmaxf(lab, t0);
    float sm = expf(lab - mx) + expf(t0 - mx) + expf(t1 - mx)
             + expf(t2 - mx) + expf(t3 - mx);
    float loss = valid ? (logf(sm) + mx - lab) : 0.0f;

    __shared__ float s_loss[WPB * 4];
    if (s == 0) s_loss[(wid << 2) | g] = loss;
    __syncthreads();
    if (threadIdx.x == 0) {
        float acc = 0.0f;
        #pragma unroll
        for (int i = 0; i < WPB * 4; ++i) acc += s_loss[i];
        partial[blockIdx.x] = acc;
    }
}

// Generic fallback (1 row per 64-lane wave) for shapes != C=1000.
__device__ __forceinline__ void grab(float4 &v, int q, int qL, int sub, float &labv) {
    if (q == qL) {
        labv = (sub == 0) ? v.x : (sub == 1) ? v.y : (sub == 2) ? v.z : v.w;
        if      (sub == 0) v.x = -INFINITY;
        else if (sub == 1) v.y = -INFINITY;
        else if (sub == 2) v.z = -INFINITY;
        else               v.w = -INFINITY;
    }
}

__global__ __launch_bounds__(256) void topk_generic(
    const float* __restrict__ logits, const int* __restrict__ labels,
    float* __restrict__ partial, int B, int C)
{
    const int wid  = threadIdx.x >> 6;
    const int lane = threadIdx.x & 63;
    const int row  = blockIdx.x * WPB + wid;

    __shared__ float s_loss[WPB];
    float loss = 0.0f;
    if (row < B) {
        const float4* rp = (const float4*)(logits + (size_t)row * (size_t)C);
        const int nq  = C >> 2;
        const int L   = labels[row];
        const int qL  = L >> 2;
        const int sub = L & 3;

        float t0 = -INFINITY, t1 = -INFINITY, t2 = -INFINITY, t3 = -INFINITY;
        float labv = -INFINITY;
        for (int q = lane; q < nq; q += 64) {
            float4 v = rp[q];
            grab(v, q, qL, sub, labv);
            sort4d(v);
            merge4(v.x, v.y, v.z, v.w, t0, t1, t2, t3);
        }
        for (int c = (nq << 2) + lane; c < C; c += 64) {
            float v = logits[(size_t)row * (size_t)C + c];
            if (c == L) { labv = v; v = -INFINITY; }
            merge4(v, -INFINITY, -INFINITY, -INFINITY, t0, t1, t2, t3);
        }
        float lab = labv;
        #pragma unroll
        for (int m = 1; m < 64; m <<= 1) {
            float o0 = __shfl_xor(t0, m, 64);
            float o1 = __shfl_xor(t1, m, 64);
            float o2 = __shfl_xor(t2, m, 64);
            float o3 = __shfl_xor(t3, m, 64);
            float ol = __shfl_xor(lab, m, 64);
            merge4(o0, o1, o2, o3, t0, t1, t2, t3);
            lab = fmaxf(lab, ol);
        }
        float mx = fmaxf(lab, t0);
        float sm = expf(lab - mx) + expf(t0 - mx) + expf(t1 - mx)
                 + expf(t2 - mx) + expf(t3 - mx);
        loss = logf(sm) + mx - lab;
    }

    if (lane == 0) s_loss[wid] = loss;
    __syncthreads();
    if (threadIdx.x == 0)
        partial[blockIdx.x] = s_loss[0] + s_loss[1] + s_loss[2] + s_loss[3];
}

__global__ __launch_bounds__(256) void reduce_partials(
    const float* __restrict__ partial, float* __restrict__ out, int n, float invB)
{
    __shared__ float s_sum[WPB];
    float s = 0.0f;
    if ((n & 3) == 0) {
        const float4* p4 = (const float4*)partial;
        const int n4 = n >> 2;
        float s0 = 0, s1 = 0, s2 = 0, s3 = 0;
        for (int i = threadIdx.x; i < n4; i += 1024) {
            int i0 = i, i1 = i + 256, i2 = i + 512, i3 = i + 768;
            if (i0 < n4) { float4 v = p4[i0]; s0 += (v.x + v.y) + (v.z + v.w); }
            if (i1 < n4) { float4 v = p4[i1]; s1 += (v.x + v.y) + (v.z + v.w); }
            if (i2 < n4) { float4 v = p4[i2]; s2 += (v.x + v.y) + (v.z + v.w); }
            if (i3 < n4) { float4 v = p4[i3]; s3 += (v.x + v.y) + (v.z + v.w); }
        }
        s = (s0 + s1) + (s2 + s3);
    } else {
        for (int i = threadIdx.x; i < n; i += 256) s += partial[i];
    }
    #pragma unroll
    for (int m = 32; m >= 1; m >>= 1) s += __shfl_down(s, m, 64);
    const int wid  = threadIdx.x >> 6;
    const int lane = threadIdx.x & 63;
    if (lane == 0) s_sum[wid] = s;
    __syncthreads();
    if (threadIdx.x == 0)
        *out = (s_sum[0] + s_sum[1] + s_sum[2] + s_sum[3]) * invB;
}

extern "C" void kernel_launch(void* const* d_in, const int* in_sizes, int n_in,
                              void* d_out, int out_size, void* d_ws, size_t ws_size,
                              hipStream_t stream) {
    const float* logits = (const float*)d_in[0];
    const int*   labels = (const int*)d_in[1];
    float*       out    = (float*)d_out;
    float*       part   = (float*)d_ws;

    const int B = in_sizes[1];
    const int C = in_sizes[0] / B;        // 1000 for this problem

    if (C == 1000) {
        const int rows_per_block = 4 * WPB;                          // 16
        const int grid = (B + rows_per_block - 1) / rows_per_block;  // 2048
        topk16<250><<<grid, WPB * 64, 0, stream>>>(logits, labels, part, B);
        reduce_partials<<<1, 256, 0, stream>>>(part, out, grid, 1.0f / (float)B);
    } else {
        const int grid = (B + WPB - 1) / WPB;
        topk_generic<<<grid, WPB * 64, 0, stream>>>(logits, labels, part, B, C);
        reduce_partials<<<1, 256, 0, stream>>>(part, out, grid, 1.0f / (float)B);
    }
}

// Round 8
// 180.329 us; speedup vs baseline: 1.0165x; 1.0165x over previous
//
#include <hip/hip_runtime.h>
#include <math.h>

// GradientBoostingLoss: per-row top-4 hardest negatives + logsumexp, mean over rows.
// R8 = R6 revert (best measured: 177.8 us). 16 lanes/row, 4 rows/wave. Label +
// label-logit gathered FIRST so data-load consumption order == issue order
// (fine-grained vmcnt, no full drain). All 16 data loads issued before first
// consume (R7 proved halving in-flight depth regresses). Nontemporal streaming
// loads. All-DPP 4-stage butterfly (zero DS ops). launch_bounds(256,4).

#define WPB 4   // waves per block (256 threads)

typedef float vf4 __attribute__((ext_vector_type(4)));

__device__ __forceinline__ float4 ntload(const float* p) {
    vf4 v = __builtin_nontemporal_load((const vf4*)p);
    return make_float4(v.x, v.y, v.z, v.w);
}

__device__ __forceinline__ void ce(float &a, float &b) {
    float hi = fmaxf(a, b), lo = fminf(a, b); a = hi; b = lo;
}

// Sort float4 descending: 5 compare-exchanges.
__device__ __forceinline__ void sort4d(float4 &v) {
    ce(v.x, v.y); ce(v.z, v.w); ce(v.x, v.z); ce(v.y, v.w); ce(v.y, v.z);
}

// Merge two sorted-desc top-4 lists -> sorted-desc top-4 of union (12 ops).
__device__ __forceinline__ void merge4(float o0, float o1, float o2, float o3,
                                       float &t0, float &t1, float &t2, float &t3) {
    float c0 = fmaxf(t0, o3);
    float c1 = fmaxf(t1, o2);
    float c2 = fmaxf(t2, o1);
    float c3 = fmaxf(t3, o0);
    float d0 = fmaxf(c0, c2), d2 = fminf(c0, c2);
    float d1 = fmaxf(c1, c3), d3 = fminf(c1, c3);
    t0 = fmaxf(d0, d1); t1 = fminf(d0, d1);
    t2 = fmaxf(d2, d3); t3 = fminf(d2, d3);
}

__device__ __forceinline__ void mrgv(float4 &d, const float4 s) {
    merge4(s.x, s.y, s.z, s.w, d.x, d.y, d.z, d.w);
}

// Mask the label element to -inf if it lives in quad q (value already gathered).
__device__ __forceinline__ void maskq(float4 &v, int q, int qL, int sub) {
    if (q == qL) {
        if      (sub == 0) v.x = -INFINITY;
        else if (sub == 1) v.y = -INFINITY;
        else if (sub == 2) v.z = -INFINITY;
        else               v.w = -INFINITY;
    }
}

// DPP cross-lane (row-local, VALU-speed). 0xB1=xor1, 0x4E=xor2, 0x124=row_ror:4, 0x128=row_ror:8.
template<int CTRL>
__device__ __forceinline__ float dppf(float x) {
    int i = __float_as_int(x);
    return __int_as_float(__builtin_amdgcn_update_dpp(i, i, CTRL, 0xF, 0xF, false));
}

// NQ = quads per row; requires 239 < NQ <= 256.
template<int NQ>
__global__ __launch_bounds__(256, 4) void topk16(
    const float* __restrict__ logits, const int* __restrict__ labels,
    float* __restrict__ partial, int B)
{
    static_assert(NQ > 239 && NQ <= 256, "topk16 requires 239 < NQ <= 256");
    const int wid  = threadIdx.x >> 6;
    const int lane = threadIdx.x & 63;
    const int s    = lane & 15;          // sublane within 16-lane row group
    const int g    = lane >> 4;          // row group 0..3

    const int rowraw = (blockIdx.x * WPB + wid) * 4 + g;
    const bool valid = rowraw < B;
    const int row    = valid ? rowraw : B - 1;
    const float* rowp = logits + (size_t)row * (size_t)(NQ * 4);

    // ---- label chain FIRST: these two loads are issued before any data load,
    // so consuming a0 later only needs the oldest vmcnt slots (no full drain).
    const int L  = labels[row];
    const int qL = L >> 2, sub = L & 3;
    const float lab = rowp[L];           // 16 lanes/group hit the same address (broadcast)

    // ---- 16 streaming data loads, issue order == consumption order.
    const bool v15 = (s + 240) < NQ;
    const int  q15 = v15 ? (s + 240) : (NQ - 1);
    float4 a0  = ntload(rowp + 4 * (s));
    float4 a1  = ntload(rowp + 4 * (s + 16));
    float4 a2  = ntload(rowp + 4 * (s + 32));
    float4 a3  = ntload(rowp + 4 * (s + 48));
    float4 a4  = ntload(rowp + 4 * (s + 64));
    float4 a5  = ntload(rowp + 4 * (s + 80));
    float4 a6  = ntload(rowp + 4 * (s + 96));
    float4 a7  = ntload(rowp + 4 * (s + 112));
    float4 a8  = ntload(rowp + 4 * (s + 128));
    float4 a9  = ntload(rowp + 4 * (s + 144));
    float4 a10 = ntload(rowp + 4 * (s + 160));
    float4 a11 = ntload(rowp + 4 * (s + 176));
    float4 a12 = ntload(rowp + 4 * (s + 192));
    float4 a13 = ntload(rowp + 4 * (s + 208));
    float4 a14 = ntload(rowp + 4 * (s + 224));
    float4 a15 = ntload(rowp + 4 * q15);

    // ---- consume in arrival order; two parallel merge chains for ILP while
    // later loads are still in flight.
    maskq(a0, s,      qL, sub); sort4d(a0);
    maskq(a1, s + 16, qL, sub); sort4d(a1);
    float4 t = a0; mrgv(t, a1);                   // chain A
    maskq(a2, s + 32, qL, sub); sort4d(a2);
    maskq(a3, s + 48, qL, sub); sort4d(a3);
    float4 u = a2; mrgv(u, a3);                   // chain B
    maskq(a4, s + 64, qL, sub); sort4d(a4); mrgv(t, a4);
    maskq(a5, s + 80, qL, sub); sort4d(a5); mrgv(u, a5);
    maskq(a6, s + 96, qL, sub); sort4d(a6); mrgv(t, a6);
    maskq(a7, s + 112, qL, sub); sort4d(a7); mrgv(u, a7);
    maskq(a8, s + 128, qL, sub); sort4d(a8); mrgv(t, a8);
    maskq(a9, s + 144, qL, sub); sort4d(a9); mrgv(u, a9);
    maskq(a10, s + 160, qL, sub); sort4d(a10); mrgv(t, a10);
    maskq(a11, s + 176, qL, sub); sort4d(a11); mrgv(u, a11);
    maskq(a12, s + 192, qL, sub); sort4d(a12); mrgv(t, a12);
    maskq(a13, s + 208, qL, sub); sort4d(a13); mrgv(u, a13);
    maskq(a14, s + 224, qL, sub); sort4d(a14); mrgv(t, a14);
    maskq(a15, q15,     qL, sub);
    if (!v15) a15 = make_float4(-INFINITY, -INFINITY, -INFINITY, -INFINITY);
    sort4d(a15); mrgv(u, a15);
    mrgv(t, u);
    float t0 = t.x, t1 = t.y, t2 = t.z, t3 = t.w;

    // ---- 4-stage all-DPP butterfly within each 16-lane row group.
    // xor1, xor2 (quad-local), then ror:4 and ror:8 merge disjoint groups:
    // every source element counted exactly once (top-k-safe).
    #define BSTAGE(CTRL) do {                                                  \
        float o0 = dppf<CTRL>(t0), o1 = dppf<CTRL>(t1);                        \
        float o2 = dppf<CTRL>(t2), o3 = dppf<CTRL>(t3);                        \
        merge4(o0, o1, o2, o3, t0, t1, t2, t3);                                \
    } while (0)
    BSTAGE(0xB1);   // quad_perm [1,0,3,2] : xor 1
    BSTAGE(0x4E);   // quad_perm [2,3,0,1] : xor 2
    BSTAGE(0x124);  // row_ror:4
    BSTAGE(0x128);  // row_ror:8
    #undef BSTAGE

    // loss = logsumexp([lab, t0..t3]) - lab (uniform across the 16-lane group)
    float mx = fmaxf(lab, t0);
    float sm = expf(lab - mx) + expf(t0 - mx) + expf(t1 - mx)
             + expf(t2 - mx) + expf(t3 - mx);
    float loss = valid ? (logf(sm) + mx - lab) : 0.0f;

    __shared__ float s_loss[WPB * 4];
    if (s == 0) s_loss[(wid << 2) | g] = loss;
    __syncthreads();
    if (threadIdx.x == 0) {
        float acc = 0.0f;
        #pragma unroll
        for (int i = 0; i < WPB * 4; ++i) acc += s_loss[i];
        partial[blockIdx.x] = acc;
    }
}

// Generic fallback (1 row per 64-lane wave) for shapes != C=1000.
__device__ __forceinline__ void grab(float4 &v, int q, int qL, int sub, float &labv) {
    if (q == qL) {
        labv = (sub == 0) ? v.x : (sub == 1) ? v.y : (sub == 2) ? v.z : v.w;
        if      (sub == 0) v.x = -INFINITY;
        else if (sub == 1) v.y = -INFINITY;
        else if (sub == 2) v.z = -INFINITY;
        else               v.w = -INFINITY;
    }
}

__global__ __launch_bounds__(256) void topk_generic(
    const float* __restrict__ logits, const int* __restrict__ labels,
    float* __restrict__ partial, int B, int C)
{
    const int wid  = threadIdx.x >> 6;
    const int lane = threadIdx.x & 63;
    const int row  = blockIdx.x * WPB + wid;

    __shared__ float s_loss[WPB];
    float loss = 0.0f;
    if (row < B) {
        const float4* rp = (const float4*)(logits + (size_t)row * (size_t)C);
        const int nq  = C >> 2;
        const int L   = labels[row];
        const int qL  = L >> 2;
        const int sub = L & 3;

        float t0 = -INFINITY, t1 = -INFINITY, t2 = -INFINITY, t3 = -INFINITY;
        float labv = -INFINITY;
        for (int q = lane; q < nq; q += 64) {
            float4 v = rp[q];
            grab(v, q, qL, sub, labv);
            sort4d(v);
            merge4(v.x, v.y, v.z, v.w, t0, t1, t2, t3);
        }
        for (int c = (nq << 2) + lane; c < C; c += 64) {
            float v = logits[(size_t)row * (size_t)C + c];
            if (c == L) { labv = v; v = -INFINITY; }
            merge4(v, -INFINITY, -INFINITY, -INFINITY, t0, t1, t2, t3);
        }
        float lab = labv;
        #pragma unroll
        for (int m = 1; m < 64; m <<= 1) {
            float o0 = __shfl_xor(t0, m, 64);
            float o1 = __shfl_xor(t1, m, 64);
            float o2 = __shfl_xor(t2, m, 64);
            float o3 = __shfl_xor(t3, m, 64);
            float ol = __shfl_xor(lab, m, 64);
            merge4(o0, o1, o2, o3, t0, t1, t2, t3);
            lab = fmaxf(lab, ol);
        }
        float mx = fmaxf(lab, t0);
        float sm = expf(lab - mx) + expf(t0 - mx) + expf(t1 - mx)
                 + expf(t2 - mx) + expf(t3 - mx);
        loss = logf(sm) + mx - lab;
    }

    if (lane == 0) s_loss[wid] = loss;
    __syncthreads();
    if (threadIdx.x == 0)
        partial[blockIdx.x] = s_loss[0] + s_loss[1] + s_loss[2] + s_loss[3];
}

__global__ __launch_bounds__(256) void reduce_partials(
    const float* __restrict__ partial, float* __restrict__ out, int n, float invB)
{
    __shared__ float s_sum[WPB];
    float s = 0.0f;
    if ((n & 3) == 0) {
        const float4* p4 = (const float4*)partial;
        const int n4 = n >> 2;
        float s0 = 0, s1 = 0, s2 = 0, s3 = 0;
        for (int i = threadIdx.x; i < n4; i += 1024) {
            int i0 = i, i1 = i + 256, i2 = i + 512, i3 = i + 768;
            if (i0 < n4) { float4 v = p4[i0]; s0 += (v.x + v.y) + (v.z + v.w); }
            if (i1 < n4) { float4 v = p4[i1]; s1 += (v.x + v.y) + (v.z + v.w); }
            if (i2 < n4) { float4 v = p4[i2]; s2 += (v.x + v.y) + (v.z + v.w); }
            if (i3 < n4) { float4 v = p4[i3]; s3 += (v.x + v.y) + (v.z + v.w); }
        }
        s = (s0 + s1) + (s2 + s3);
    } else {
        for (int i = threadIdx.x; i < n; i += 256) s += partial[i];
    }
    #pragma unroll
    for (int m = 32; m >= 1; m >>= 1) s += __shfl_down(s, m, 64);
    const int wid  = threadIdx.x >> 6;
    const int lane = threadIdx.x & 63;
    if (lane == 0) s_sum[wid] = s;
    __syncthreads();
    if (threadIdx.x == 0)
        *out = (s_sum[0] + s_sum[1] + s_sum[2] + s_sum[3]) * invB;
}

extern "C" void kernel_launch(void* const* d_in, const int* in_sizes, int n_in,
                              void* d_out, int out_size, void* d_ws, size_t ws_size,
                              hipStream_t stream) {
    const float* logits = (const float*)d_in[0];
    const int*   labels = (const int*)d_in[1];
    float*       out    = (float*)d_out;
    float*       part   = (float*)d_ws;

    const int B = in_sizes[1];
    const int C = in_sizes[0] / B;        // 1000 for this problem

    if (C == 1000) {
        const int rows_per_block = 4 * WPB;                          // 16
        const int grid = (B + rows_per_block - 1) / rows_per_block;  // 2048
        topk16<250><<<grid, WPB * 64, 0, stream>>>(logits, labels, part, B);
        reduce_partials<<<1, 256, 0, stream>>>(part, out, grid, 1.0f / (float)B);
    } else {
        const int grid = (B + WPB - 1) / WPB;
        topk_generic<<<grid, WPB * 64, 0, stream>>>(logits, labels, part, B, C);
        reduce_partials<<<1, 256, 0, stream>>>(part, out, grid, 1.0f / (float)B);
    }
}